// Round 1
// baseline (1472.140 us; speedup 1.0000x reference)
//
#include <hip/hip_runtime.h>

#define IN_F 128

// ---------------- degree count via atomics ----------------
__global__ void k_degree(const int* __restrict__ src, const int* __restrict__ dst,
                         float* __restrict__ dout, float* __restrict__ din, int nE) {
    int i = blockIdx.x * blockDim.x + threadIdx.x;
    if (i < nE) {
        atomicAdd(&dout[src[i]], 1.0f);
        atomicAdd(&din[dst[i]], 1.0f);
    }
}

// ---------------- deg -> rsqrt(max(deg,1)) ----------------
__global__ void k_invsqrt(float* __restrict__ dout, float* __restrict__ din, int nN) {
    int i = blockIdx.x * blockDim.x + threadIdx.x;
    if (i < nN) {
        dout[i] = rsqrtf(fmaxf(dout[i], 1.0f));
        din[i]  = rsqrtf(fmaxf(din[i], 1.0f));
    }
}

// ---------------- edge scatter: agg[dst] += feat[src] * dinv_out[src] ----------------
// 32 lanes per edge, each lane handles 4 contiguous feats (float4 load, 4 scalar atomics)
__global__ __launch_bounds__(256) void k_scatter(
    const float* __restrict__ feat, const int* __restrict__ src,
    const int* __restrict__ dst, const float* __restrict__ dinv,
    float* __restrict__ agg, int nE) {
    int total = nE * 32;
    for (int idx = blockIdx.x * blockDim.x + threadIdx.x; idx < total;
         idx += gridDim.x * blockDim.x) {
        int e = idx >> 5;
        int j = (idx & 31) << 2;
        int s = src[e];
        int d = dst[e];
        float sc = dinv[s];
        const float4 v = *reinterpret_cast<const float4*>(feat + s * IN_F + j);
        float* o = agg + d * IN_F + j;
        atomicAdd(o + 0, v.x * sc);
        atomicAdd(o + 1, v.y * sc);
        atomicAdd(o + 2, v.z * sc);
        atomicAdd(o + 3, v.w * sc);
    }
}

// ---------------- out = (agg @ W) * dinv_in[:,None] + bias ----------------
// W (128x128, 64KB) fully staged in LDS. Block = 256 threads = 8 row-groups.
// Each thread: 4 rows x 4 cols accumulators; k-loop in float4 chunks.
__global__ __launch_bounds__(256) void k_gemm(
    const float* __restrict__ agg, const float* __restrict__ W,
    const float* __restrict__ bias, const float* __restrict__ dinv_in,
    float* __restrict__ out, int nN) {
    __shared__ float Wl[128 * 128];
    for (int i = threadIdx.x * 4; i < 128 * 128; i += 256 * 4)
        *reinterpret_cast<float4*>(&Wl[i]) = *reinterpret_cast<const float4*>(&W[i]);
    __syncthreads();

    const int lane = threadIdx.x & 31;
    const int rg   = threadIdx.x >> 5;
    const int col  = lane * 4;
    const int r0   = blockIdx.x * 32 + rg * 4;

    float acc[4][4];
#pragma unroll
    for (int m = 0; m < 4; ++m)
#pragma unroll
        for (int c = 0; c < 4; ++c) acc[m][c] = 0.0f;

    int r[4];
#pragma unroll
    for (int m = 0; m < 4; ++m) r[m] = min(r0 + m, nN - 1);  // clamp loads, guard stores

#pragma unroll 4
    for (int k = 0; k < 128; k += 4) {
        const float4 w0 = *reinterpret_cast<const float4*>(&Wl[(k + 0) * 128 + col]);
        const float4 w1 = *reinterpret_cast<const float4*>(&Wl[(k + 1) * 128 + col]);
        const float4 w2 = *reinterpret_cast<const float4*>(&Wl[(k + 2) * 128 + col]);
        const float4 w3 = *reinterpret_cast<const float4*>(&Wl[(k + 3) * 128 + col]);
#pragma unroll
        for (int m = 0; m < 4; ++m) {
            const float4 a = *reinterpret_cast<const float4*>(&agg[r[m] * 128 + k]);
            acc[m][0] = fmaf(a.w, w3.x, fmaf(a.z, w2.x, fmaf(a.y, w1.x, fmaf(a.x, w0.x, acc[m][0]))));
            acc[m][1] = fmaf(a.w, w3.y, fmaf(a.z, w2.y, fmaf(a.y, w1.y, fmaf(a.x, w0.y, acc[m][1]))));
            acc[m][2] = fmaf(a.w, w3.z, fmaf(a.z, w2.z, fmaf(a.y, w1.z, fmaf(a.x, w0.z, acc[m][2]))));
            acc[m][3] = fmaf(a.w, w3.w, fmaf(a.z, w2.w, fmaf(a.y, w1.w, fmaf(a.x, w0.w, acc[m][3]))));
        }
    }

    const float4 b4 = *reinterpret_cast<const float4*>(&bias[col]);
#pragma unroll
    for (int m = 0; m < 4; ++m) {
        int rr = r0 + m;
        if (rr < nN) {
            float s = dinv_in[rr];
            float4 o;
            o.x = acc[m][0] * s + b4.x;
            o.y = acc[m][1] * s + b4.y;
            o.z = acc[m][2] * s + b4.z;
            o.w = acc[m][3] * s + b4.w;
            *reinterpret_cast<float4*>(&out[rr * 128 + col]) = o;
        }
    }
}

extern "C" void kernel_launch(void* const* d_in, const int* in_sizes, int n_in,
                              void* d_out, int out_size, void* d_ws, size_t ws_size,
                              hipStream_t stream) {
    const float* feat = (const float*)d_in[0];
    const int*   src  = (const int*)d_in[1];
    const int*   dst  = (const int*)d_in[2];
    const float* W    = (const float*)d_in[3];
    const float* bias = (const float*)d_in[4];
    float*       out  = (float*)d_out;

    const int nE = in_sizes[1];
    const int nN = in_sizes[0] / IN_F;

    float* deg_out = (float*)d_ws;
    float* deg_in  = deg_out + nN;
    float* agg     = deg_in + nN;   // offset 2*nN floats = 400000 B, 16B aligned

    size_t zero_bytes = (size_t)(2 * nN) * sizeof(float) + (size_t)nN * IN_F * sizeof(float);
    hipMemsetAsync(d_ws, 0, zero_bytes, stream);

    k_degree<<<(nE + 255) / 256, 256, 0, stream>>>(src, dst, deg_out, deg_in, nE);
    k_invsqrt<<<(nN + 255) / 256, 256, 0, stream>>>(deg_out, deg_in, nN);
    k_scatter<<<2048, 256, 0, stream>>>(feat, src, dst, deg_out, agg, nE);
    k_gemm<<<(nN + 31) / 32, 256, 0, stream>>>(agg, W, bias, deg_in, out, nN);
}

// Round 2
// 301.722 us; speedup vs baseline: 4.8791x; 4.8791x over previous
//
#include <hip/hip_runtime.h>

#define IN_F 128
#define SCAN_T 1024

// ---------------- degree histogram (int atomics) ----------------
__global__ void k_degree(const int* __restrict__ src, const int* __restrict__ dst,
                         int* __restrict__ cnt_out, int* __restrict__ cnt_in, int nE) {
    int i = blockIdx.x * blockDim.x + threadIdx.x;
    if (i < nE) {
        atomicAdd(&cnt_out[src[i]], 1);
        atomicAdd(&cnt_in[dst[i]], 1);
    }
}

// ---------------- exclusive scan of cnt_in -> offs[0..nN], offs[nN]=nE ----------------
__global__ __launch_bounds__(SCAN_T) void k_scan(const int* __restrict__ cnt,
                                                 int* __restrict__ offs, int nN) {
    __shared__ int part[SCAN_T];
    int t = threadIdx.x;
    int chunk = (nN + SCAN_T - 1) / SCAN_T;
    int b = t * chunk;
    int e = min(b + chunk, nN);
    int s = 0;
    for (int i = b; i < e; ++i) s += cnt[i];
    part[t] = s;
    __syncthreads();
    for (int d = 1; d < SCAN_T; d <<= 1) {
        int v = (t >= d) ? part[t - d] : 0;
        __syncthreads();
        part[t] += v;
        __syncthreads();
    }
    int run = (t > 0) ? part[t - 1] : 0;
    for (int i = b; i < e; ++i) { offs[i] = run; run += cnt[i]; }
    if (t == SCAN_T - 1) offs[nN] = run;
}

// ---------------- counts -> rsqrt(max(c,1)), in place (int -> float) ----------------
__global__ void k_invsqrt(int* __restrict__ a, int* __restrict__ b, int nN) {
    int i = blockIdx.x * blockDim.x + threadIdx.x;
    if (i < nN) {
        float va = rsqrtf(fmaxf((float)a[i], 1.0f));
        float vb = rsqrtf(fmaxf((float)b[i], 1.0f));
        reinterpret_cast<float*>(a)[i] = va;
        reinterpret_cast<float*>(b)[i] = vb;
    }
}

// ---------------- bucket edges by dst: eidx holds src sorted by dst ----------------
__global__ void k_bin(const int* __restrict__ src, const int* __restrict__ dst,
                      const int* __restrict__ offs, int* __restrict__ cursor,
                      int* __restrict__ eidx, int nE) {
    int i = blockIdx.x * blockDim.x + threadIdx.x;
    if (i < nE) {
        int d = dst[i];
        int p = offs[d] + atomicAdd(&cursor[d], 1);
        eidx[p] = src[i];
    }
}

// ---------------- gather: agg[d] = sum_{e in bin(d)} feat[src_e] * dinv_out[src_e] ----
// one wave (64 lanes) per node; lane owns 2 contiguous feats (float2).
__global__ __launch_bounds__(256) void k_gather(
    const float* __restrict__ feat, const int* __restrict__ eidx,
    const int* __restrict__ offs, const float* __restrict__ dinv,
    float* __restrict__ agg, int nN) {
    int node = blockIdx.x * 4 + (threadIdx.x >> 6);
    if (node >= nN) return;
    int lane = threadIdx.x & 63;
    int beg = offs[node], end = offs[node + 1];

    float2 acc = make_float2(0.0f, 0.0f);
    for (int base = beg; base < end; base += 64) {
        int n = end - base;
        if (n > 64) n = 64;
        int s_l = 0; float sc_l = 0.0f;
        if (lane < n) { s_l = eidx[base + lane]; sc_l = dinv[s_l]; }
        int i = 0;
        for (; i + 1 < n; i += 2) {
            int   s0 = __shfl(s_l, i),     s1 = __shfl(s_l, i + 1);
            float c0 = __shfl(sc_l, i),    c1 = __shfl(sc_l, i + 1);
            const float2 v0 = *reinterpret_cast<const float2*>(feat + (size_t)s0 * IN_F + lane * 2);
            const float2 v1 = *reinterpret_cast<const float2*>(feat + (size_t)s1 * IN_F + lane * 2);
            acc.x = fmaf(v0.x, c0, acc.x);
            acc.y = fmaf(v0.y, c0, acc.y);
            acc.x = fmaf(v1.x, c1, acc.x);
            acc.y = fmaf(v1.y, c1, acc.y);
        }
        if (i < n) {
            int   s0 = __shfl(s_l, i);
            float c0 = __shfl(sc_l, i);
            const float2 v0 = *reinterpret_cast<const float2*>(feat + (size_t)s0 * IN_F + lane * 2);
            acc.x = fmaf(v0.x, c0, acc.x);
            acc.y = fmaf(v0.y, c0, acc.y);
        }
    }
    *reinterpret_cast<float2*>(agg + (size_t)node * IN_F + lane * 2) = acc;
}

// ---------------- out = (agg @ W) * dinv_in[:,None] + bias ----------------
__global__ __launch_bounds__(256) void k_gemm(
    const float* __restrict__ agg, const float* __restrict__ W,
    const float* __restrict__ bias, const float* __restrict__ dinv_in,
    float* __restrict__ out, int nN) {
    __shared__ float Wl[128 * 128];
    for (int i = threadIdx.x * 4; i < 128 * 128; i += 256 * 4)
        *reinterpret_cast<float4*>(&Wl[i]) = *reinterpret_cast<const float4*>(&W[i]);
    __syncthreads();

    const int lane = threadIdx.x & 31;
    const int rg   = threadIdx.x >> 5;
    const int col  = lane * 4;
    const int r0   = blockIdx.x * 32 + rg * 4;

    float acc[4][4];
#pragma unroll
    for (int m = 0; m < 4; ++m)
#pragma unroll
        for (int c = 0; c < 4; ++c) acc[m][c] = 0.0f;

    int r[4];
#pragma unroll
    for (int m = 0; m < 4; ++m) r[m] = min(r0 + m, nN - 1);

#pragma unroll 4
    for (int k = 0; k < 128; k += 4) {
        const float4 w0 = *reinterpret_cast<const float4*>(&Wl[(k + 0) * 128 + col]);
        const float4 w1 = *reinterpret_cast<const float4*>(&Wl[(k + 1) * 128 + col]);
        const float4 w2 = *reinterpret_cast<const float4*>(&Wl[(k + 2) * 128 + col]);
        const float4 w3 = *reinterpret_cast<const float4*>(&Wl[(k + 3) * 128 + col]);
#pragma unroll
        for (int m = 0; m < 4; ++m) {
            const float4 a = *reinterpret_cast<const float4*>(&agg[r[m] * 128 + k]);
            acc[m][0] = fmaf(a.w, w3.x, fmaf(a.z, w2.x, fmaf(a.y, w1.x, fmaf(a.x, w0.x, acc[m][0]))));
            acc[m][1] = fmaf(a.w, w3.y, fmaf(a.z, w2.y, fmaf(a.y, w1.y, fmaf(a.x, w0.y, acc[m][1]))));
            acc[m][2] = fmaf(a.w, w3.z, fmaf(a.z, w2.z, fmaf(a.y, w1.z, fmaf(a.x, w0.z, acc[m][2]))));
            acc[m][3] = fmaf(a.w, w3.w, fmaf(a.z, w2.w, fmaf(a.y, w1.w, fmaf(a.x, w0.w, acc[m][3]))));
        }
    }

    const float4 b4 = *reinterpret_cast<const float4*>(&bias[col]);
#pragma unroll
    for (int m = 0; m < 4; ++m) {
        int rr = r0 + m;
        if (rr < nN) {
            float s = dinv_in[rr];
            float4 o;
            o.x = acc[m][0] * s + b4.x;
            o.y = acc[m][1] * s + b4.y;
            o.z = acc[m][2] * s + b4.z;
            o.w = acc[m][3] * s + b4.w;
            *reinterpret_cast<float4*>(&out[rr * 128 + col]) = o;
        }
    }
}

extern "C" void kernel_launch(void* const* d_in, const int* in_sizes, int n_in,
                              void* d_out, int out_size, void* d_ws, size_t ws_size,
                              hipStream_t stream) {
    const float* feat = (const float*)d_in[0];
    const int*   src  = (const int*)d_in[1];
    const int*   dst  = (const int*)d_in[2];
    const float* W    = (const float*)d_in[3];
    const float* bias = (const float*)d_in[4];
    float*       out  = (float*)d_out;

    const int nE = in_sizes[1];
    const int nN = in_sizes[0] / IN_F;

    // workspace layout (all 4B elems; agg first for 16B alignment)
    float* agg     = (float*)d_ws;
    int*   cnt_out = (int*)(agg + (size_t)nN * IN_F);
    int*   cnt_in  = cnt_out + nN;
    int*   cursor  = cnt_in + nN;
    int*   offs    = cursor + nN;
    int*   eidx    = offs + nN + 1;
    float* dinv_out = (float*)cnt_out;  // in-place int->float after k_invsqrt
    float* dinv_in  = (float*)cnt_in;

    // zero the three counter arrays only (agg is fully written by k_gather)
    hipMemsetAsync(cnt_out, 0, (size_t)3 * nN * sizeof(int), stream);

    k_degree <<<(nE + 255) / 256, 256, 0, stream>>>(src, dst, cnt_out, cnt_in, nE);
    k_scan   <<<1, SCAN_T, 0, stream>>>(cnt_in, offs, nN);
    k_invsqrt<<<(nN + 255) / 256, 256, 0, stream>>>(cnt_out, cnt_in, nN);
    k_bin    <<<(nE + 255) / 256, 256, 0, stream>>>(src, dst, offs, cursor, eidx, nE);
    k_gather <<<(nN + 3) / 4, 256, 0, stream>>>(feat, eidx, offs, dinv_out, agg, nN);
    k_gemm   <<<(nN + 31) / 32, 256, 0, stream>>>(agg, W, bias, dinv_in, out, nN);
}

// Round 3
// 227.075 us; speedup vs baseline: 6.4830x; 1.3287x over previous
//
#include <hip/hip_runtime.h>

#define IN_F 128

// ---------------- degree histogram (int atomics) ----------------
__global__ void k_degree(const int* __restrict__ src, const int* __restrict__ dst,
                         int* __restrict__ cnt_out, int* __restrict__ cnt_in, int nE) {
    int i = blockIdx.x * blockDim.x + threadIdx.x;
    if (i < nE) {
        atomicAdd(&cnt_out[src[i]], 1);
        atomicAdd(&cnt_in[dst[i]], 1);
    }
}

// ---------------- hierarchical exclusive scan: cnt_in -> offs ----------------
// pass 1: each block scans 1024 elems (256 thr x int4), writes block sum
__global__ __launch_bounds__(256) void k_scan_blk(const int* __restrict__ cnt,
                                                  int* __restrict__ offs,
                                                  int* __restrict__ part, int nN) {
    __shared__ int ts[256];
    const int t = threadIdx.x;
    const int base = blockIdx.x * 1024 + t * 4;
    int4 v = make_int4(0, 0, 0, 0);
    if (base + 3 < nN) {
        v = *reinterpret_cast<const int4*>(cnt + base);
    } else {
        if (base + 0 < nN) v.x = cnt[base + 0];
        if (base + 1 < nN) v.y = cnt[base + 1];
        if (base + 2 < nN) v.z = cnt[base + 2];
        if (base + 3 < nN) v.w = cnt[base + 3];
    }
    const int s = v.x + v.y + v.z + v.w;
    ts[t] = s;
    __syncthreads();
    for (int d = 1; d < 256; d <<= 1) {
        int u = (t >= d) ? ts[t - d] : 0;
        __syncthreads();
        ts[t] += u;
        __syncthreads();
    }
    const int ex = ts[t] - s;  // exclusive prefix of this thread within block
    if (t == 255) part[blockIdx.x] = ts[255];
    int4 o;
    o.x = ex;
    o.y = o.x + v.x;
    o.z = o.y + v.y;
    o.w = o.z + v.z;
    if (base + 3 < nN) {
        *reinterpret_cast<int4*>(offs + base) = o;
    } else {
        if (base + 0 < nN) offs[base + 0] = o.x;
        if (base + 1 < nN) offs[base + 1] = o.y;
        if (base + 2 < nN) offs[base + 2] = o.z;
        if (base + 3 < nN) offs[base + 3] = o.w;
    }
}

// pass 2: exclusive scan of block partials (single block, up to 256 blocks)
__global__ __launch_bounds__(256) void k_scan_top(int* __restrict__ part, int nb) {
    __shared__ int ts[256];
    const int t = threadIdx.x;
    const int v = (t < nb) ? part[t] : 0;
    ts[t] = v;
    __syncthreads();
    for (int d = 1; d < 256; d <<= 1) {
        int u = (t >= d) ? ts[t - d] : 0;
        __syncthreads();
        ts[t] += u;
        __syncthreads();
    }
    if (t < nb) part[t] = ts[t] - v;  // exclusive
}

// pass 3: add block offset; write sentinel offs[nN] = nE
__global__ __launch_bounds__(256) void k_scan_add(int* __restrict__ offs,
                                                  const int* __restrict__ part,
                                                  int nN, int nE) {
    const int base = blockIdx.x * 1024 + threadIdx.x * 4;
    const int add = part[blockIdx.x];
    if (base + 3 < nN) {
        int4 o = *reinterpret_cast<int4*>(offs + base);
        o.x += add; o.y += add; o.z += add; o.w += add;
        *reinterpret_cast<int4*>(offs + base) = o;
    } else {
#pragma unroll
        for (int j = 0; j < 4; ++j)
            if (base + j < nN) offs[base + j] += add;
    }
    if (blockIdx.x == 0 && threadIdx.x == 0) offs[nN] = nE;
}

// ---------------- counts -> rsqrt(max(c,1)), in place (int -> float) ----------------
__global__ void k_invsqrt(int* __restrict__ a, int* __restrict__ b, int nN) {
    int i = blockIdx.x * blockDim.x + threadIdx.x;
    if (i < nN) {
        float va = rsqrtf(fmaxf((float)a[i], 1.0f));
        float vb = rsqrtf(fmaxf((float)b[i], 1.0f));
        reinterpret_cast<float*>(a)[i] = va;
        reinterpret_cast<float*>(b)[i] = vb;
    }
}

// ---------------- bucket edges by dst: eidx holds src sorted by dst ----------------
__global__ void k_bin(const int* __restrict__ src, const int* __restrict__ dst,
                      const int* __restrict__ offs, int* __restrict__ cursor,
                      int* __restrict__ eidx, int nE) {
    int i = blockIdx.x * blockDim.x + threadIdx.x;
    if (i < nE) {
        int d = dst[i];
        int p = offs[d] + atomicAdd(&cursor[d], 1);
        eidx[p] = src[i];
    }
}

// ---------------- gather: agg[d] = sum_{e in bin(d)} feat[src_e] * dinv_out[src_e] ----
// one wave (64 lanes) per node; lane owns 2 contiguous feats (float2).
__global__ __launch_bounds__(256) void k_gather(
    const float* __restrict__ feat, const int* __restrict__ eidx,
    const int* __restrict__ offs, const float* __restrict__ dinv,
    float* __restrict__ agg, int nN) {
    int node = blockIdx.x * 4 + (threadIdx.x >> 6);
    if (node >= nN) return;
    int lane = threadIdx.x & 63;
    int beg = offs[node], end = offs[node + 1];

    float2 acc = make_float2(0.0f, 0.0f);
    for (int base = beg; base < end; base += 64) {
        int n = end - base;
        if (n > 64) n = 64;
        int s_l = 0; float sc_l = 0.0f;
        if (lane < n) { s_l = eidx[base + lane]; sc_l = dinv[s_l]; }
        int i = 0;
        for (; i + 1 < n; i += 2) {
            int   s0 = __shfl(s_l, i),     s1 = __shfl(s_l, i + 1);
            float c0 = __shfl(sc_l, i),    c1 = __shfl(sc_l, i + 1);
            const float2 v0 = *reinterpret_cast<const float2*>(feat + (size_t)s0 * IN_F + lane * 2);
            const float2 v1 = *reinterpret_cast<const float2*>(feat + (size_t)s1 * IN_F + lane * 2);
            acc.x = fmaf(v0.x, c0, acc.x);
            acc.y = fmaf(v0.y, c0, acc.y);
            acc.x = fmaf(v1.x, c1, acc.x);
            acc.y = fmaf(v1.y, c1, acc.y);
        }
        if (i < n) {
            int   s0 = __shfl(s_l, i);
            float c0 = __shfl(sc_l, i);
            const float2 v0 = *reinterpret_cast<const float2*>(feat + (size_t)s0 * IN_F + lane * 2);
            acc.x = fmaf(v0.x, c0, acc.x);
            acc.y = fmaf(v0.y, c0, acc.y);
        }
    }
    *reinterpret_cast<float2*>(agg + (size_t)node * IN_F + lane * 2) = acc;
}

// ---------------- out = (agg @ W) * dinv_in[:,None] + bias ----------------
__global__ __launch_bounds__(256) void k_gemm(
    const float* __restrict__ agg, const float* __restrict__ W,
    const float* __restrict__ bias, const float* __restrict__ dinv_in,
    float* __restrict__ out, int nN) {
    __shared__ float Wl[128 * 128];
    for (int i = threadIdx.x * 4; i < 128 * 128; i += 256 * 4)
        *reinterpret_cast<float4*>(&Wl[i]) = *reinterpret_cast<const float4*>(&W[i]);
    __syncthreads();

    const int lane = threadIdx.x & 31;
    const int rg   = threadIdx.x >> 5;
    const int col  = lane * 4;
    const int r0   = blockIdx.x * 32 + rg * 4;

    float acc[4][4];
#pragma unroll
    for (int m = 0; m < 4; ++m)
#pragma unroll
        for (int c = 0; c < 4; ++c) acc[m][c] = 0.0f;

    int r[4];
#pragma unroll
    for (int m = 0; m < 4; ++m) r[m] = min(r0 + m, nN - 1);

#pragma unroll 4
    for (int k = 0; k < 128; k += 4) {
        const float4 w0 = *reinterpret_cast<const float4*>(&Wl[(k + 0) * 128 + col]);
        const float4 w1 = *reinterpret_cast<const float4*>(&Wl[(k + 1) * 128 + col]);
        const float4 w2 = *reinterpret_cast<const float4*>(&Wl[(k + 2) * 128 + col]);
        const float4 w3 = *reinterpret_cast<const float4*>(&Wl[(k + 3) * 128 + col]);
#pragma unroll
        for (int m = 0; m < 4; ++m) {
            const float4 a = *reinterpret_cast<const float4*>(&agg[r[m] * 128 + k]);
            acc[m][0] = fmaf(a.w, w3.x, fmaf(a.z, w2.x, fmaf(a.y, w1.x, fmaf(a.x, w0.x, acc[m][0]))));
            acc[m][1] = fmaf(a.w, w3.y, fmaf(a.z, w2.y, fmaf(a.y, w1.y, fmaf(a.x, w0.y, acc[m][1]))));
            acc[m][2] = fmaf(a.w, w3.z, fmaf(a.z, w2.z, fmaf(a.y, w1.z, fmaf(a.x, w0.z, acc[m][2]))));
            acc[m][3] = fmaf(a.w, w3.w, fmaf(a.z, w2.w, fmaf(a.y, w1.w, fmaf(a.x, w0.w, acc[m][3]))));
        }
    }

    const float4 b4 = *reinterpret_cast<const float4*>(&bias[col]);
#pragma unroll
    for (int m = 0; m < 4; ++m) {
        int rr = r0 + m;
        if (rr < nN) {
            float s = dinv_in[rr];
            float4 o;
            o.x = acc[m][0] * s + b4.x;
            o.y = acc[m][1] * s + b4.y;
            o.z = acc[m][2] * s + b4.z;
            o.w = acc[m][3] * s + b4.w;
            *reinterpret_cast<float4*>(&out[rr * 128 + col]) = o;
        }
    }
}

extern "C" void kernel_launch(void* const* d_in, const int* in_sizes, int n_in,
                              void* d_out, int out_size, void* d_ws, size_t ws_size,
                              hipStream_t stream) {
    const float* feat = (const float*)d_in[0];
    const int*   src  = (const int*)d_in[1];
    const int*   dst  = (const int*)d_in[2];
    const float* W    = (const float*)d_in[3];
    const float* bias = (const float*)d_in[4];
    float*       out  = (float*)d_out;

    const int nE = in_sizes[1];
    const int nN = in_sizes[0] / IN_F;
    const int nb = (nN + 1023) / 1024;  // scan blocks (49 for 50000)

    // workspace layout (all 4B elems; agg first for 16B alignment)
    float* agg     = (float*)d_ws;
    int*   cnt_out = (int*)(agg + (size_t)nN * IN_F);
    int*   cnt_in  = cnt_out + nN;
    int*   cursor  = cnt_in + nN;
    int*   offs    = cursor + nN;
    int*   part    = offs + nN + 1;
    int*   eidx    = part + 256;
    float* dinv_out = (float*)cnt_out;  // in-place int->float after k_invsqrt
    float* dinv_in  = (float*)cnt_in;

    // zero the three counter arrays only (agg is fully written by k_gather)
    hipMemsetAsync(cnt_out, 0, (size_t)3 * nN * sizeof(int), stream);

    k_degree  <<<(nE + 255) / 256, 256, 0, stream>>>(src, dst, cnt_out, cnt_in, nE);
    k_scan_blk<<<nb, 256, 0, stream>>>(cnt_in, offs, part, nN);
    k_scan_top<<<1, 256, 0, stream>>>(part, nb);
    k_scan_add<<<nb, 256, 0, stream>>>(offs, part, nN, nE);
    k_invsqrt <<<(nN + 255) / 256, 256, 0, stream>>>(cnt_out, cnt_in, nN);
    k_bin     <<<(nE + 255) / 256, 256, 0, stream>>>(src, dst, offs, cursor, eidx, nE);
    k_gather  <<<(nN + 3) / 4, 256, 0, stream>>>(feat, eidx, offs, dinv_out, agg, nN);
    k_gemm    <<<(nN + 31) / 32, 256, 0, stream>>>(agg, W, bias, dinv_in, out, nN);
}

// Round 4
// 179.176 us; speedup vs baseline: 8.2162x; 1.2673x over previous
//
#include <hip/hip_runtime.h>

#define IN_F 128
#define HC 32            // edge chunks for privatized histogram
#define HR 4             // node ranges (range hist fits in 64KB LDS)
#define RSIZE_MAX 12544  // >= ceil(nN/HR) for nN=50000

// ---------------- privatized histogram: no global atomics ----------------
// grid = 2*HR*HC blocks: kind (0=src,1=dst) x node-range r x edge-chunk c.
// Each block LDS-counts keys of its chunk falling in its range, then writes
// the partial histogram contiguously to part[kind][c][range slice].
__global__ __launch_bounds__(256) void k_hist(const int* __restrict__ src,
                                              const int* __restrict__ dst,
                                              int* __restrict__ part,
                                              int nN, int nE) {
    __shared__ int h[RSIZE_MAX];
    const int bid  = blockIdx.x;
    const int kind = bid / (HR * HC);
    const int rem  = bid % (HR * HC);
    const int r    = rem / HC;
    const int c    = rem % HC;
    const int rs   = (nN + HR - 1) / HR;       // nominal range size
    const int rbeg = r * rs;
    const int rsize = min(rs, nN - rbeg);
    if (rsize <= 0) return;                    // uniform per block

    const int* key = kind ? dst : src;

    for (int i = threadIdx.x; i < rsize; i += 256) h[i] = 0;
    __syncthreads();

    const int chunk = (nE + HC - 1) / HC;
    const int ebeg = c * chunk;
    const int eend = min(ebeg + chunk, nE);

    if ((ebeg & 3) == 0) {  // vectorized path (16B-aligned chunk start)
        for (int i = ebeg + threadIdx.x * 4; i < eend; i += 256 * 4) {
            if (i + 3 < eend) {
                const int4 k4 = *reinterpret_cast<const int4*>(key + i);
                int a;
                a = k4.x - rbeg; if ((unsigned)a < (unsigned)rsize) atomicAdd(&h[a], 1);
                a = k4.y - rbeg; if ((unsigned)a < (unsigned)rsize) atomicAdd(&h[a], 1);
                a = k4.z - rbeg; if ((unsigned)a < (unsigned)rsize) atomicAdd(&h[a], 1);
                a = k4.w - rbeg; if ((unsigned)a < (unsigned)rsize) atomicAdd(&h[a], 1);
            } else {
                for (int j = i; j < eend; ++j) {
                    int a = key[j] - rbeg;
                    if ((unsigned)a < (unsigned)rsize) atomicAdd(&h[a], 1);
                }
            }
        }
    } else {
        for (int i = ebeg + threadIdx.x; i < eend; i += 256) {
            int a = key[i] - rbeg;
            if ((unsigned)a < (unsigned)rsize) atomicAdd(&h[a], 1);
        }
    }
    __syncthreads();

    int* pout = part + ((size_t)kind * HC + c) * nN + rbeg;
    for (int i = threadIdx.x; i < rsize; i += 256) pout[i] = h[i];
}

// ---------------- merge partials; emit cnt_in (for scan) + both rsqrt scales ----
__global__ void k_merge(const int* __restrict__ part, int* __restrict__ cnt_in,
                        float* __restrict__ dinv_out, float* __restrict__ dinv_in,
                        int nN) {
    const int n = blockIdx.x * blockDim.x + threadIdx.x;
    if (n >= nN) return;
    int s = 0, d = 0;
#pragma unroll 4
    for (int c = 0; c < HC; ++c) {
        s += part[(size_t)c * nN + n];
        d += part[((size_t)HC + c) * nN + n];
    }
    cnt_in[n]   = d;
    dinv_out[n] = rsqrtf(fmaxf((float)s, 1.0f));
    dinv_in[n]  = rsqrtf(fmaxf((float)d, 1.0f));
}

// ---------------- hierarchical exclusive scan: cnt_in -> offs ----------------
__global__ __launch_bounds__(256) void k_scan_blk(const int* __restrict__ cnt,
                                                  int* __restrict__ offs,
                                                  int* __restrict__ part, int nN) {
    __shared__ int ts[256];
    const int t = threadIdx.x;
    const int base = blockIdx.x * 1024 + t * 4;
    int4 v = make_int4(0, 0, 0, 0);
    if (base + 3 < nN) {
        v = *reinterpret_cast<const int4*>(cnt + base);
    } else {
        if (base + 0 < nN) v.x = cnt[base + 0];
        if (base + 1 < nN) v.y = cnt[base + 1];
        if (base + 2 < nN) v.z = cnt[base + 2];
        if (base + 3 < nN) v.w = cnt[base + 3];
    }
    const int s = v.x + v.y + v.z + v.w;
    ts[t] = s;
    __syncthreads();
    for (int d = 1; d < 256; d <<= 1) {
        int u = (t >= d) ? ts[t - d] : 0;
        __syncthreads();
        ts[t] += u;
        __syncthreads();
    }
    const int ex = ts[t] - s;
    if (t == 255) part[blockIdx.x] = ts[255];
    int4 o;
    o.x = ex;
    o.y = o.x + v.x;
    o.z = o.y + v.y;
    o.w = o.z + v.z;
    if (base + 3 < nN) {
        *reinterpret_cast<int4*>(offs + base) = o;
    } else {
        if (base + 0 < nN) offs[base + 0] = o.x;
        if (base + 1 < nN) offs[base + 1] = o.y;
        if (base + 2 < nN) offs[base + 2] = o.z;
        if (base + 3 < nN) offs[base + 3] = o.w;
    }
}

__global__ __launch_bounds__(256) void k_scan_top(int* __restrict__ part, int nb) {
    __shared__ int ts[256];
    const int t = threadIdx.x;
    const int v = (t < nb) ? part[t] : 0;
    ts[t] = v;
    __syncthreads();
    for (int d = 1; d < 256; d <<= 1) {
        int u = (t >= d) ? ts[t - d] : 0;
        __syncthreads();
        ts[t] += u;
        __syncthreads();
    }
    if (t < nb) part[t] = ts[t] - v;
}

__global__ __launch_bounds__(256) void k_scan_add(int* __restrict__ offs,
                                                  const int* __restrict__ part,
                                                  int nN, int nE) {
    const int base = blockIdx.x * 1024 + threadIdx.x * 4;
    const int add = part[blockIdx.x];
    if (base + 3 < nN) {
        int4 o = *reinterpret_cast<int4*>(offs + base);
        o.x += add; o.y += add; o.z += add; o.w += add;
        *reinterpret_cast<int4*>(offs + base) = o;
    } else {
#pragma unroll
        for (int j = 0; j < 4; ++j)
            if (base + j < nN) offs[base + j] += add;
    }
    if (blockIdx.x == 0 && threadIdx.x == 0) offs[nN] = nE;
}

// ---------------- bucket edges by dst: eidx holds src sorted by dst ----------------
__global__ void k_bin(const int* __restrict__ src, const int* __restrict__ dst,
                      const int* __restrict__ offs, int* __restrict__ cursor,
                      int* __restrict__ eidx, int nE) {
    int i = blockIdx.x * blockDim.x + threadIdx.x;
    if (i < nE) {
        int d = dst[i];
        int p = offs[d] + atomicAdd(&cursor[d], 1);
        eidx[p] = src[i];
    }
}

// ---------------- gather: agg[d] = sum_{e in bin(d)} feat[src_e] * dinv_out[src_e] ----
__global__ __launch_bounds__(256) void k_gather(
    const float* __restrict__ feat, const int* __restrict__ eidx,
    const int* __restrict__ offs, const float* __restrict__ dinv,
    float* __restrict__ agg, int nN) {
    int node = blockIdx.x * 4 + (threadIdx.x >> 6);
    if (node >= nN) return;
    int lane = threadIdx.x & 63;
    int beg = offs[node], end = offs[node + 1];

    float2 acc = make_float2(0.0f, 0.0f);
    for (int base = beg; base < end; base += 64) {
        int n = end - base;
        if (n > 64) n = 64;
        int s_l = 0; float sc_l = 0.0f;
        if (lane < n) { s_l = eidx[base + lane]; sc_l = dinv[s_l]; }
        int i = 0;
        for (; i + 1 < n; i += 2) {
            int   s0 = __shfl(s_l, i),     s1 = __shfl(s_l, i + 1);
            float c0 = __shfl(sc_l, i),    c1 = __shfl(sc_l, i + 1);
            const float2 v0 = *reinterpret_cast<const float2*>(feat + (size_t)s0 * IN_F + lane * 2);
            const float2 v1 = *reinterpret_cast<const float2*>(feat + (size_t)s1 * IN_F + lane * 2);
            acc.x = fmaf(v0.x, c0, acc.x);
            acc.y = fmaf(v0.y, c0, acc.y);
            acc.x = fmaf(v1.x, c1, acc.x);
            acc.y = fmaf(v1.y, c1, acc.y);
        }
        if (i < n) {
            int   s0 = __shfl(s_l, i);
            float c0 = __shfl(sc_l, i);
            const float2 v0 = *reinterpret_cast<const float2*>(feat + (size_t)s0 * IN_F + lane * 2);
            acc.x = fmaf(v0.x, c0, acc.x);
            acc.y = fmaf(v0.y, c0, acc.y);
        }
    }
    *reinterpret_cast<float2*>(agg + (size_t)node * IN_F + lane * 2) = acc;
}

// ---------------- out = (agg @ W) * dinv_in[:,None] + bias ----------------
__global__ __launch_bounds__(256) void k_gemm(
    const float* __restrict__ agg, const float* __restrict__ W,
    const float* __restrict__ bias, const float* __restrict__ dinv_in,
    float* __restrict__ out, int nN) {
    __shared__ float Wl[128 * 128];
    for (int i = threadIdx.x * 4; i < 128 * 128; i += 256 * 4)
        *reinterpret_cast<float4*>(&Wl[i]) = *reinterpret_cast<const float4*>(&W[i]);
    __syncthreads();

    const int lane = threadIdx.x & 31;
    const int rg   = threadIdx.x >> 5;
    const int col  = lane * 4;
    const int r0   = blockIdx.x * 32 + rg * 4;

    float acc[4][4];
#pragma unroll
    for (int m = 0; m < 4; ++m)
#pragma unroll
        for (int c = 0; c < 4; ++c) acc[m][c] = 0.0f;

    int r[4];
#pragma unroll
    for (int m = 0; m < 4; ++m) r[m] = min(r0 + m, nN - 1);

#pragma unroll 4
    for (int k = 0; k < 128; k += 4) {
        const float4 w0 = *reinterpret_cast<const float4*>(&Wl[(k + 0) * 128 + col]);
        const float4 w1 = *reinterpret_cast<const float4*>(&Wl[(k + 1) * 128 + col]);
        const float4 w2 = *reinterpret_cast<const float4*>(&Wl[(k + 2) * 128 + col]);
        const float4 w3 = *reinterpret_cast<const float4*>(&Wl[(k + 3) * 128 + col]);
#pragma unroll
        for (int m = 0; m < 4; ++m) {
            const float4 a = *reinterpret_cast<const float4*>(&agg[r[m] * 128 + k]);
            acc[m][0] = fmaf(a.w, w3.x, fmaf(a.z, w2.x, fmaf(a.y, w1.x, fmaf(a.x, w0.x, acc[m][0]))));
            acc[m][1] = fmaf(a.w, w3.y, fmaf(a.z, w2.y, fmaf(a.y, w1.y, fmaf(a.x, w0.y, acc[m][1]))));
            acc[m][2] = fmaf(a.w, w3.z, fmaf(a.z, w2.z, fmaf(a.y, w1.z, fmaf(a.x, w0.z, acc[m][2]))));
            acc[m][3] = fmaf(a.w, w3.w, fmaf(a.z, w2.w, fmaf(a.y, w1.w, fmaf(a.x, w0.w, acc[m][3]))));
        }
    }

    const float4 b4 = *reinterpret_cast<const float4*>(&bias[col]);
#pragma unroll
    for (int m = 0; m < 4; ++m) {
        int rr = r0 + m;
        if (rr < nN) {
            float s = dinv_in[rr];
            float4 o;
            o.x = acc[m][0] * s + b4.x;
            o.y = acc[m][1] * s + b4.y;
            o.z = acc[m][2] * s + b4.z;
            o.w = acc[m][3] * s + b4.w;
            *reinterpret_cast<float4*>(&out[rr * 128 + col]) = o;
        }
    }
}

extern "C" void kernel_launch(void* const* d_in, const int* in_sizes, int n_in,
                              void* d_out, int out_size, void* d_ws, size_t ws_size,
                              hipStream_t stream) {
    const float* feat = (const float*)d_in[0];
    const int*   src  = (const int*)d_in[1];
    const int*   dst  = (const int*)d_in[2];
    const float* W    = (const float*)d_in[3];
    const float* bias = (const float*)d_in[4];
    float*       out  = (float*)d_out;

    const int nE = in_sizes[1];
    const int nN = in_sizes[0] / IN_F;
    const int nb = (nN + 1023) / 1024;  // scan blocks

    // workspace layout:
    //  region0 (25.6MB): hist partials [2][HC][nN] (12.8MB), dead after k_merge,
    //                    then reused as agg [nN][128] written by k_gather.
    float* agg      = (float*)d_ws;
    int*   part_h   = (int*)d_ws;
    int*   cnt_in   = (int*)(agg + (size_t)nN * IN_F);
    int*   cursor   = cnt_in + nN;
    int*   offs     = cursor + nN;
    int*   partscan = offs + nN + 1;
    int*   eidx     = partscan + 256;
    float* dinv_out = (float*)(eidx + nE);
    float* dinv_in  = dinv_out + nN;

    hipMemsetAsync(cursor, 0, (size_t)nN * sizeof(int), stream);

    k_hist    <<<2 * HR * HC, 256, 0, stream>>>(src, dst, part_h, nN, nE);
    k_merge   <<<(nN + 255) / 256, 256, 0, stream>>>(part_h, cnt_in, dinv_out, dinv_in, nN);
    k_scan_blk<<<nb, 256, 0, stream>>>(cnt_in, offs, partscan, nN);
    k_scan_top<<<1, 256, 0, stream>>>(partscan, nb);
    k_scan_add<<<nb, 256, 0, stream>>>(offs, partscan, nN, nE);
    k_bin     <<<(nE + 255) / 256, 256, 0, stream>>>(src, dst, offs, cursor, eidx, nE);
    k_gather  <<<(nN + 3) / 4, 256, 0, stream>>>(feat, eidx, offs, dinv_out, agg, nN);
    k_gemm    <<<(nN + 31) / 32, 256, 0, stream>>>(agg, W, bias, dinv_in, out, nN);
}